// Round 21
// baseline (81.745 us; speedup 1.0000x reference)
//
#include <hip/hip_runtime.h>
#include <math.h>

// SSIM (16,3,512,512) fp32, 11x11 separable Gaussian, VALID -> per-batch mean [16].
//
// Round-21: EXACT round-16 inner loop (best: 59.4us), repackaged as 1-WAVE
// blocks. R16's four waves are already fully independent (private LDS regions,
// private DMA, no main-loop barriers) -- the 256-thread block was only a
// residency quantum. 64-thread blocks drop LDS/block to 14.1KB -> 11 blocks/CU
// by LDS = 11 waves/CU (vs 8), with identical registers, instructions, and
// LDS traffic. Also deletes the end-of-block barrier + LDS reduce (wave shfl
// + one atomicAdd per wave).
//  - Wave owns a 128-output-col strip (2 cols/thread); global_load_lds
//    staging; per-wave counted vmcnt(24) is the only synchronization.
//  - Channel-interleaved LDS float4(r,d,r,d); packed fp32 math (v_pk_fma_f32
//    via __builtin_elementwise_fma), {mu_r,mu_d}/{E_rr+dd,E_rd} as f32x2.
//  - 255x scaling cancels: C1 = 1e-4, C2 = 9e-4 on [0,1] data.

#define WSZ 11
#define IMG 512
#define OSZ 502
#define NT  64
#define CH_OUT 32
#define NCHUNK 16        // 16*32 >= 502
#define NSLOT 11
#define LA 6             // lookahead rows

struct WinArg { float w[WSZ]; };

typedef float f2 __attribute__((ext_vector_type(2)));
typedef float f4v __attribute__((ext_vector_type(4)));

typedef const __attribute__((address_space(1))) unsigned int* gp_t;
typedef __attribute__((address_space(3))) unsigned int* sp_t;

#define C1V 1.0e-4f
#define C2V 9.0e-4f

__device__ __forceinline__ void pkfma(f2& acc, f2 a, f2 b) {
    acc = __builtin_elementwise_fma(a, b, acc);   // v_pk_fma_f32
}

__global__ __launch_bounds__(NT, 3) void ssim_w1(
    const float* __restrict__ rawp, const float* __restrict__ dstp,
    float* __restrict__ out, WinArg wa, float inv_n)
{
    // strips 0-2: 11 slots x 80 float4; strip 3 uses 11 x 64 of the same
    __shared__ f4v srow[NSLOT * 80];         // 14080 B -> 11 blocks/CU by LDS

    const int lane  = threadIdx.x;
    const int strip = blockIdx.x & 3;
    const int chunk = blockIdx.x >> 2;
    const int img   = blockIdx.y;

    const int o0    = chunk * CH_OUT;
    const int olim  = min(o0 + CH_OUT, OSZ);
    const int rlast = min(o0 + CH_OUT + WSZ - 2, IMG - 1);
    const int NR    = rlast - o0 + 1;        // 42 (32 for last chunk)

    const bool w3     = (strip == 3);
    const int  nch    = w3 ? 4 : 5;          // DMA chunks per row (uniform)
    const int  slotf4 = w3 ? 64 : 80;        // float4 per slot (uniform)
    f4v* region = srow;
    const int  rl     = (w3 && lane > 58) ? 58 : lane;   // read clamp
    const bool active = !(w3 && lane > 58);

    const size_t ibase = (size_t)img * (size_t)(IMG * IMG);
    // lane parity -> channel; (lane>>1) -> col within 32-col chunk
    const float* lane_base = ((lane & 1) ? dstp : rawp) + ibase
                           + (size_t)(strip * 128 + (lane >> 1));

    // packed weights
    f2 wv[WSZ];
#pragma unroll
    for (int j = 0; j < WSZ; ++j) { wv[j].x = wa.w[j]; wv[j].y = wa.w[j]; }

#define STAGE(ROW, SLOT)                                                       \
    {                                                                          \
        const float* _s = lane_base + (size_t)(ROW) * IMG;                     \
        float* _d = (float*)(region + (SLOT) * slotf4);                        \
        _Pragma("unroll")                                                      \
        for (int _c = 0; _c < 5; ++_c) {                                       \
            if (_c < nch)                                                      \
                __builtin_amdgcn_global_load_lds(                              \
                    (gp_t)(const void*)(_s + 32 * _c),                         \
                    (sp_t)(void*)(_d + 64 * _c), 4, 0, 0);                     \
        }                                                                      \
    }

    f2 hs12[WSZ][2];                         // ring: [slot][col] {mu_r, mu_d}
    f2 hs34[WSZ][2];                         // ring: [slot][col] {E_rr+dd, E_rd}
    float acc = 0.0f;

    // prologue: rows 0..LA-1 in flight (slots 0..5)
#pragma unroll
    for (int r = 0; r < LA; ++r) STAGE(o0 + r, r)

#pragma unroll 1
    for (int rr = 0; rr < NR; rr += WSZ) {
#pragma unroll
        for (int k = 0; k < WSZ; ++k) {
            const int klin = rr + k;
            if (klin < NR) {                 // wave-uniform
                // stage row klin+LA (clamped tail restage lands in dead slot)
                {
                    int rs = klin + LA; if (rs > NR - 1) rs = NR - 1;
                    STAGE(o0 + rs, (k + LA) % NSLOT)
                }
                // per-wave wait: guarantees row klin's loads complete
                asm volatile("s_waitcnt vmcnt(24)" ::: "memory");

                f4v q[6];
                {
                    const f4v* rp = region + k * slotf4 + rl;
#pragma unroll
                    for (int j = 0; j < 6; ++j) q[j] = rp[j];
                }

                // ---- H-pass, 2 cols, packed channels ----
                f2 s12a = {0.f, 0.f}, s34a = {0.f, 0.f};
                f2 s12b = {0.f, 0.f}, s34b = {0.f, 0.f};
#pragma unroll
                for (int e = 0; e < 12; ++e) {
                    const f2 rd = (e & 1) ? q[e >> 1].zw : q[e >> 1].xy;
                    const f2 rr2 = rd * rd;                // v_pk_mul_f32
                    f2 sp;                                 // (r^2+d^2, r*d)
                    sp.x = rr2.x + rr2.y;
                    sp.y = rd.x * rd.y;
                    if (e < 11) {            // col a tap e
                        pkfma(s12a, wv[e], rd);
                        pkfma(s34a, wv[e], sp);
                    }
                    if (e >= 1) {            // col b tap e-1
                        pkfma(s12b, wv[e - 1], rd);
                        pkfma(s34b, wv[e - 1], sp);
                    }
                }
                hs12[k][0] = s12a; hs34[k][0] = s34a;
                hs12[k][1] = s12b; hs34[k][1] = s34b;

                // ---- V-pass + SSIM ----
                const int o = o0 + klin - (WSZ - 1);
                if (klin >= WSZ - 1 && o < olim && active) {
                    f2 m12a = {0.f, 0.f}, m34a = {0.f, 0.f};
                    f2 m12b = {0.f, 0.f}, m34b = {0.f, 0.f};
#pragma unroll
                    for (int i = 0; i < WSZ; ++i) {
                        const int s = (k + 1 + i) % WSZ;   // static after unroll
                        pkfma(m12a, wv[i], hs12[s][0]);
                        pkfma(m34a, wv[i], hs34[s][0]);
                        pkfma(m12b, wv[i], hs12[s][1]);
                        pkfma(m34b, wv[i], hs34[s][1]);
                    }
                    {
                        const float m1 = m12a.x, m2 = m12a.y;
                        const float m3 = m34a.x, m4 = m34a.y;
                        const float q1 = m1 * m1, q2 = m2 * m2, mm = m1 * m2;
                        const float num = (2.f * mm + C1V) * (2.f * (m4 - mm) + C2V);
                        const float den = (q1 + q2 + C1V) * (((m3 - q1) - q2) + C2V);
                        acc += num * __builtin_amdgcn_rcpf(den);
                    }
                    {
                        const float m1 = m12b.x, m2 = m12b.y;
                        const float m3 = m34b.x, m4 = m34b.y;
                        const float q1 = m1 * m1, q2 = m2 * m2, mm = m1 * m2;
                        const float num = (2.f * mm + C1V) * (2.f * (m4 - mm) + C2V);
                        const float den = (q1 + q2 + C1V) * (((m3 - q1) - q2) + C2V);
                        acc += num * __builtin_amdgcn_rcpf(den);
                    }
                }
            }
        }
    }
#undef STAGE

    // ---- wave reduction -> one atomicAdd per wave (no barrier needed) ----
#pragma unroll
    for (int off = 32; off > 0; off >>= 1) acc += __shfl_down(acc, off, 64);
    if (lane == 0) atomicAdd(out + img / 3, acc * inv_n);
}

extern "C" void kernel_launch(void* const* d_in, const int* in_sizes, int n_in,
                              void* d_out, int out_size, void* d_ws, size_t ws_size,
                              hipStream_t stream) {
    const float* raw = (const float*)d_in[0];
    const float* dst = (const float*)d_in[1];
    float* out = (float*)d_out;

    hipMemsetAsync(out, 0, (size_t)out_size * sizeof(float), stream);

    WinArg wa;
    double g[WSZ], s = 0.0;
    for (int i = 0; i < WSZ; ++i) {
        double ax = (double)i - (double)(WSZ - 1) / 2.0;
        g[i] = exp(-(ax * ax) / (2.0 * 1.5 * 1.5));
        s += g[i];
    }
    for (int i = 0; i < WSZ; ++i) wa.w[i] = (float)(g[i] / s);

    const float inv_n = (float)(1.0 / (3.0 * (double)OSZ * (double)OSZ));

    dim3 grid(4 * NCHUNK, 48);
    ssim_w1<<<grid, NT, 0, stream>>>(raw, dst, out, wa, inv_n);
}

// Round 22
// 68.115 us; speedup vs baseline: 1.2001x; 1.2001x over previous
//
#include <hip/hip_runtime.h>
#include <math.h>

// SSIM (16,3,512,512) fp32, 11x11 separable Gaussian, VALID -> per-batch mean [16].
//
// Round-22: EXACT round-16 kernel (best: 59.4us) with ONE change:
// CH_OUT 32 -> 42 (NCHUNK 12). Halo redundancy drops from 42/32=1.31 to
// 52/42=1.24; total staged row-work is 0.94x. R19 validated time ~ c*work
// while the grid saturates (576 blocks = 2.25/CU, still >= 2 resident/CU).
//  - Each wave owns a 128-output-col strip (2 cols/thread) and stages its own
//    rows via global_load_lds; per-wave vmcnt(24) is the only synchronization.
//  - Channel-interleaved LDS float4(r,d,r,d); packed fp32 math (v_pk_fma_f32
//    via __builtin_elementwise_fma), {mu_r,mu_d}/{E_rr+dd,E_rd} as f32x2.
//  - 255x scaling cancels: C1 = 1e-4, C2 = 9e-4 on [0,1] data.

#define WSZ 11
#define IMG 512
#define OSZ 502
#define NT  256
#define CH_OUT 42
#define NCHUNK 12        // 12*42 = 504 >= 502
#define NSLOT 11
#define LA 6             // lookahead rows

struct WinArg { float w[WSZ]; };

typedef float f2 __attribute__((ext_vector_type(2)));
typedef float f4v __attribute__((ext_vector_type(4)));

typedef const __attribute__((address_space(1))) unsigned int* gp_t;
typedef __attribute__((address_space(3))) unsigned int* sp_t;

#define C1V 1.0e-4f
#define C2V 9.0e-4f

__device__ __forceinline__ void pkfma(f2& acc, f2 a, f2 b) {
    acc = __builtin_elementwise_fma(a, b, acc);   // v_pk_fma_f32
}

__global__ __launch_bounds__(NT, 3) void ssim_w42(
    const float* __restrict__ rawp, const float* __restrict__ dstp,
    float* __restrict__ out, WinArg wa, float inv_n)
{
    // waves 0-2: 11 slots x 80 float4 (880 f4 each); wave 3: 11 x 64 (704 f4)
    __shared__ f4v srow[3344];               // 53504 B
    __shared__ float wred[NT / 64];

    const int tid  = threadIdx.x;
    const int lane = tid & 63;
    const int wave = tid >> 6;
    const int chunk = blockIdx.x;
    const int img   = blockIdx.y;

    const int o0    = chunk * CH_OUT;
    const int olim  = min(o0 + CH_OUT, OSZ);
    const int rlast = min(o0 + CH_OUT + WSZ - 2, IMG - 1);
    const int NR    = rlast - o0 + 1;        // 52 (50 for last chunk)

    const bool w3     = (wave == 3);
    const int  nch    = w3 ? 4 : 5;          // DMA chunks per row (wave-uniform)
    const int  slotf4 = w3 ? 64 : 80;        // float4 per slot (wave-uniform)
    f4v* region = srow + wave * 880;         // wave 3 -> 2640, uses 704 f4
    const int  rl     = (w3 && lane > 58) ? 58 : lane;   // read clamp
    const bool active = !(w3 && lane > 58);

    const size_t ibase = (size_t)img * (size_t)(IMG * IMG);
    // lane parity -> channel; (lane>>1) -> col within 32-col chunk
    const float* lane_base = ((lane & 1) ? dstp : rawp) + ibase
                           + (size_t)(wave * 128 + (lane >> 1));

    // packed weights (compiler hoists / rematerializes as it prefers)
    f2 wv[WSZ];
#pragma unroll
    for (int j = 0; j < WSZ; ++j) { wv[j].x = wa.w[j]; wv[j].y = wa.w[j]; }

#define STAGE(ROW, SLOT)                                                       \
    {                                                                          \
        const float* _s = lane_base + (size_t)(ROW) * IMG;                     \
        float* _d = (float*)(region + (SLOT) * slotf4);                        \
        _Pragma("unroll")                                                      \
        for (int _c = 0; _c < 5; ++_c) {                                       \
            if (_c < nch)                                                      \
                __builtin_amdgcn_global_load_lds(                              \
                    (gp_t)(const void*)(_s + 32 * _c),                         \
                    (sp_t)(void*)(_d + 64 * _c), 4, 0, 0);                     \
        }                                                                      \
    }

    f2 hs12[WSZ][2];                         // ring: [slot][col] {mu_r, mu_d}
    f2 hs34[WSZ][2];                         // ring: [slot][col] {E_rr+dd, E_rd}
    float acc = 0.0f;

    // prologue: rows 0..LA-1 in flight (slots 0..5)
#pragma unroll
    for (int r = 0; r < LA; ++r) STAGE(o0 + r, r)

#pragma unroll 1
    for (int rr = 0; rr < NR; rr += WSZ) {
#pragma unroll
        for (int k = 0; k < WSZ; ++k) {
            const int klin = rr + k;
            if (klin < NR) {                 // block-uniform
                // stage row klin+LA (clamped tail restage lands in dead slot)
                {
                    int rs = klin + LA; if (rs > NR - 1) rs = NR - 1;
                    STAGE(o0 + rs, (k + LA) % NSLOT)
                }
                // per-wave wait: guarantees row klin's loads complete
                asm volatile("s_waitcnt vmcnt(24)" ::: "memory");

                f4v q[6];
                {
                    const f4v* rp = region + k * slotf4 + rl;
#pragma unroll
                    for (int j = 0; j < 6; ++j) q[j] = rp[j];
                }

                // ---- H-pass, 2 cols, packed channels ----
                f2 s12a = {0.f, 0.f}, s34a = {0.f, 0.f};
                f2 s12b = {0.f, 0.f}, s34b = {0.f, 0.f};
#pragma unroll
                for (int e = 0; e < 12; ++e) {
                    const f2 rd = (e & 1) ? q[e >> 1].zw : q[e >> 1].xy;
                    const f2 rr2 = rd * rd;                // v_pk_mul_f32
                    f2 sp;                                 // (r^2+d^2, r*d)
                    sp.x = rr2.x + rr2.y;
                    sp.y = rd.x * rd.y;
                    if (e < 11) {            // col a tap e
                        pkfma(s12a, wv[e], rd);
                        pkfma(s34a, wv[e], sp);
                    }
                    if (e >= 1) {            // col b tap e-1
                        pkfma(s12b, wv[e - 1], rd);
                        pkfma(s34b, wv[e - 1], sp);
                    }
                }
                hs12[k][0] = s12a; hs34[k][0] = s34a;
                hs12[k][1] = s12b; hs34[k][1] = s34b;

                // ---- V-pass + SSIM ----
                const int o = o0 + klin - (WSZ - 1);
                if (klin >= WSZ - 1 && o < olim && active) {
                    f2 m12a = {0.f, 0.f}, m34a = {0.f, 0.f};
                    f2 m12b = {0.f, 0.f}, m34b = {0.f, 0.f};
#pragma unroll
                    for (int i = 0; i < WSZ; ++i) {
                        const int s = (k + 1 + i) % WSZ;   // static after unroll
                        pkfma(m12a, wv[i], hs12[s][0]);
                        pkfma(m34a, wv[i], hs34[s][0]);
                        pkfma(m12b, wv[i], hs12[s][1]);
                        pkfma(m34b, wv[i], hs34[s][1]);
                    }
                    {
                        const float m1 = m12a.x, m2 = m12a.y;
                        const float m3 = m34a.x, m4 = m34a.y;
                        const float q1 = m1 * m1, q2 = m2 * m2, mm = m1 * m2;
                        const float num = (2.f * mm + C1V) * (2.f * (m4 - mm) + C2V);
                        const float den = (q1 + q2 + C1V) * (((m3 - q1) - q2) + C2V);
                        acc += num * __builtin_amdgcn_rcpf(den);
                    }
                    {
                        const float m1 = m12b.x, m2 = m12b.y;
                        const float m3 = m34b.x, m4 = m34b.y;
                        const float q1 = m1 * m1, q2 = m2 * m2, mm = m1 * m2;
                        const float num = (2.f * mm + C1V) * (2.f * (m4 - mm) + C2V);
                        const float den = (q1 + q2 + C1V) * (((m3 - q1) - q2) + C2V);
                        acc += num * __builtin_amdgcn_rcpf(den);
                    }
                }
            }
        }
    }
#undef STAGE

    // ---- block reduction -> one atomicAdd per block ----
#pragma unroll
    for (int off = 32; off > 0; off >>= 1) acc += __shfl_down(acc, off, 64);
    if (lane == 0) wred[wave] = acc;
    __syncthreads();
    if (tid == 0) {
        const float tot = (wred[0] + wred[1]) + (wred[2] + wred[3]);
        atomicAdd(out + img / 3, tot * inv_n);
    }
}

extern "C" void kernel_launch(void* const* d_in, const int* in_sizes, int n_in,
                              void* d_out, int out_size, void* d_ws, size_t ws_size,
                              hipStream_t stream) {
    const float* raw = (const float*)d_in[0];
    const float* dst = (const float*)d_in[1];
    float* out = (float*)d_out;

    hipMemsetAsync(out, 0, (size_t)out_size * sizeof(float), stream);

    WinArg wa;
    double g[WSZ], s = 0.0;
    for (int i = 0; i < WSZ; ++i) {
        double ax = (double)i - (double)(WSZ - 1) / 2.0;
        g[i] = exp(-(ax * ax) / (2.0 * 1.5 * 1.5));
        s += g[i];
    }
    for (int i = 0; i < WSZ; ++i) wa.w[i] = (float)(g[i] / s);

    const float inv_n = (float)(1.0 / (3.0 * (double)OSZ * (double)OSZ));

    dim3 grid(NCHUNK, 48);
    ssim_w42<<<grid, NT, 0, stream>>>(raw, dst, out, wa, inv_n);
}

// Round 23
// 59.828 us; speedup vs baseline: 1.3663x; 1.1385x over previous
//
#include <hip/hip_runtime.h>
#include <math.h>

// SSIM (16,3,512,512) fp32, 11x11 separable Gaussian, VALID -> per-batch mean [16].
//
// Round-23: round-16 (best: 59.4us) with ONE change: the V-pass is shifted
// one row later and runs BETWEEN the q ds_read issue and the H-pass, so its
// ~110 packed-VALU ops cover the LDS read latency (the dominant measured
// stall at 2 waves/SIMD). Unlike R20, ring and LDS stay at 11 slots: the
// V-pass for output o=klin-11 reads slot k (row klin-11) BEFORE the H-pass
// overwrites it -- no extra state, no LDS growth, no occupancy change.
// One uniform-branch epilogue V-pass per block (KOFF = NR%11, static).
//  - Each wave owns a 128-output-col strip (2 cols/thread) and stages its own
//    rows via global_load_lds; per-wave vmcnt(24) is the only synchronization.
//  - Channel-interleaved LDS float4(r,d,r,d); packed fp32 math (v_pk_fma_f32
//    via __builtin_elementwise_fma), {mu_r,mu_d}/{E_rr+dd,E_rd} as f32x2.
//  - 255x scaling cancels: C1 = 1e-4, C2 = 9e-4 on [0,1] data.

#define WSZ 11
#define IMG 512
#define OSZ 502
#define NT  256
#define CH_OUT 32
#define NCHUNK 16        // 16*32 >= 502
#define NSLOT 11
#define LA 6             // lookahead rows

struct WinArg { float w[WSZ]; };

typedef float f2 __attribute__((ext_vector_type(2)));
typedef float f4v __attribute__((ext_vector_type(4)));

typedef const __attribute__((address_space(1))) unsigned int* gp_t;
typedef __attribute__((address_space(3))) unsigned int* sp_t;

#define C1V 1.0e-4f
#define C2V 9.0e-4f

__device__ __forceinline__ void pkfma(f2& acc, f2 a, f2 b) {
    acc = __builtin_elementwise_fma(a, b, acc);   // v_pk_fma_f32
}

__global__ __launch_bounds__(NT, 3) void ssim_vshift(
    const float* __restrict__ rawp, const float* __restrict__ dstp,
    float* __restrict__ out, WinArg wa, float inv_n)
{
    // waves 0-2: 11 slots x 80 float4 (880 f4 each); wave 3: 11 x 64 (704 f4)
    __shared__ f4v srow[3344];               // 53504 B (same as R16)
    __shared__ float wred[NT / 64];

    const int tid  = threadIdx.x;
    const int lane = tid & 63;
    const int wave = tid >> 6;
    const int chunk = blockIdx.x;
    const int img   = blockIdx.y;

    const int o0    = chunk * CH_OUT;
    const int olim  = min(o0 + CH_OUT, OSZ);
    const int rlast = min(o0 + CH_OUT + WSZ - 2, IMG - 1);
    const int NR    = rlast - o0 + 1;        // 42 (32 for last chunk)

    const bool w3     = (wave == 3);
    const int  nch    = w3 ? 4 : 5;          // DMA chunks per row (wave-uniform)
    const int  slotf4 = w3 ? 64 : 80;        // float4 per slot (wave-uniform)
    f4v* region = srow + wave * 880;         // wave 3 -> 2640, uses 704 f4
    const int  rl     = (w3 && lane > 58) ? 58 : lane;   // read clamp
    const bool active = !(w3 && lane > 58);

    const size_t ibase = (size_t)img * (size_t)(IMG * IMG);
    // lane parity -> channel; (lane>>1) -> col within 32-col chunk
    const float* lane_base = ((lane & 1) ? dstp : rawp) + ibase
                           + (size_t)(wave * 128 + (lane >> 1));

    // packed weights
    f2 wv[WSZ];
#pragma unroll
    for (int j = 0; j < WSZ; ++j) { wv[j].x = wa.w[j]; wv[j].y = wa.w[j]; }

#define STAGE(ROW, SLOT)                                                       \
    {                                                                          \
        const float* _s = lane_base + (size_t)(ROW) * IMG;                     \
        float* _d = (float*)(region + (SLOT) * slotf4);                        \
        _Pragma("unroll")                                                      \
        for (int _c = 0; _c < 5; ++_c) {                                       \
            if (_c < nch)                                                      \
                __builtin_amdgcn_global_load_lds(                              \
                    (gp_t)(const void*)(_s + 32 * _c),                         \
                    (sp_t)(void*)(_d + 64 * _c), 4, 0, 0);                     \
        }                                                                      \
    }

    // V-pass + SSIM for one output; ring slots (KOFF+i)%NSLOT, i=0..10 (static)
#define VPASS(KOFF)                                                            \
    {                                                                          \
        f2 m12a = {0.f, 0.f}, m34a = {0.f, 0.f};                               \
        f2 m12b = {0.f, 0.f}, m34b = {0.f, 0.f};                               \
        _Pragma("unroll")                                                      \
        for (int i = 0; i < WSZ; ++i) {                                        \
            const int s = ((KOFF) + i) % NSLOT;                                \
            pkfma(m12a, wv[i], hs12[s][0]);                                    \
            pkfma(m34a, wv[i], hs34[s][0]);                                    \
            pkfma(m12b, wv[i], hs12[s][1]);                                    \
            pkfma(m34b, wv[i], hs34[s][1]);                                    \
        }                                                                      \
        {                                                                      \
            const float m1 = m12a.x, m2 = m12a.y;                              \
            const float m3 = m34a.x, m4 = m34a.y;                              \
            const float q1 = m1 * m1, q2 = m2 * m2, mm = m1 * m2;              \
            const float num = (2.f * mm + C1V) * (2.f * (m4 - mm) + C2V);      \
            const float den = (q1 + q2 + C1V) * (((m3 - q1) - q2) + C2V);      \
            acc += num * __builtin_amdgcn_rcpf(den);                           \
        }                                                                      \
        {                                                                      \
            const float m1 = m12b.x, m2 = m12b.y;                              \
            const float m3 = m34b.x, m4 = m34b.y;                              \
            const float q1 = m1 * m1, q2 = m2 * m2, mm = m1 * m2;              \
            const float num = (2.f * mm + C1V) * (2.f * (m4 - mm) + C2V);      \
            const float den = (q1 + q2 + C1V) * (((m3 - q1) - q2) + C2V);      \
            acc += num * __builtin_amdgcn_rcpf(den);                           \
        }                                                                      \
    }

    f2 hs12[NSLOT][2];                       // ring: [slot][col] {mu_r, mu_d}
    f2 hs34[NSLOT][2];                       // ring: [slot][col] {E_rr+dd, E_rd}
    float acc = 0.0f;

    // prologue: rows 0..LA-1 in flight (slots 0..5)
#pragma unroll
    for (int r = 0; r < LA; ++r) STAGE(o0 + r, r)

#pragma unroll 1
    for (int rr = 0; rr < NR; rr += WSZ) {
#pragma unroll
        for (int k = 0; k < WSZ; ++k) {
            const int klin = rr + k;
            if (klin < NR) {                 // block-uniform
                // stage row klin+LA (clamped tail restage lands in dead slot)
                {
                    int rs = klin + LA; if (rs > NR - 1) rs = NR - 1;
                    STAGE(o0 + rs, (k + LA) % NSLOT)
                }
                // per-wave wait: guarantees row klin's loads complete
                asm volatile("s_waitcnt vmcnt(24)" ::: "memory");

                // issue q reads; the V-pass below covers their latency
                f4v q[6];
                {
                    const f4v* rp = region + k * slotf4 + rl;
#pragma unroll
                    for (int j = 0; j < 6; ++j) q[j] = rp[j];
                }

                // ---- V-pass for output o = klin-11 (ring regs only).
                // Slot k still holds row klin-11; H-pass overwrites it after.
                if (klin >= WSZ && (o0 + klin - WSZ) < olim && active)
                    VPASS(k)

                // ---- H-pass on q -> ring slot k ----
                f2 s12a = {0.f, 0.f}, s34a = {0.f, 0.f};
                f2 s12b = {0.f, 0.f}, s34b = {0.f, 0.f};
#pragma unroll
                for (int e = 0; e < 12; ++e) {
                    const f2 rd = (e & 1) ? q[e >> 1].zw : q[e >> 1].xy;
                    const f2 rr2 = rd * rd;                // v_pk_mul_f32
                    f2 sp;                                 // (r^2+d^2, r*d)
                    sp.x = rr2.x + rr2.y;
                    sp.y = rd.x * rd.y;
                    if (e < 11) {            // col a tap e
                        pkfma(s12a, wv[e], rd);
                        pkfma(s34a, wv[e], sp);
                    }
                    if (e >= 1) {            // col b tap e-1
                        pkfma(s12b, wv[e - 1], rd);
                        pkfma(s34b, wv[e - 1], sp);
                    }
                }
                hs12[k][0] = s12a; hs34[k][0] = s34a;
                hs12[k][1] = s12b; hs34[k][1] = s34b;
            }
        }
    }

    // ---- epilogue: final output o = NR-11 (rows NR-11..NR-1 in ring) ----
    if (active && (o0 + NR - WSZ) < olim) {
        if (NR == 42) { VPASS(9) }           // 42 % 11
        else          { VPASS(10) }          // 32 % 11
    }
#undef STAGE
#undef VPASS

    // ---- block reduction -> one atomicAdd per block ----
#pragma unroll
    for (int off = 32; off > 0; off >>= 1) acc += __shfl_down(acc, off, 64);
    if (lane == 0) wred[wave] = acc;
    __syncthreads();
    if (tid == 0) {
        const float tot = (wred[0] + wred[1]) + (wred[2] + wred[3]);
        atomicAdd(out + img / 3, tot * inv_n);
    }
}

extern "C" void kernel_launch(void* const* d_in, const int* in_sizes, int n_in,
                              void* d_out, int out_size, void* d_ws, size_t ws_size,
                              hipStream_t stream) {
    const float* raw = (const float*)d_in[0];
    const float* dst = (const float*)d_in[1];
    float* out = (float*)d_out;

    hipMemsetAsync(out, 0, (size_t)out_size * sizeof(float), stream);

    WinArg wa;
    double g[WSZ], s = 0.0;
    for (int i = 0; i < WSZ; ++i) {
        double ax = (double)i - (double)(WSZ - 1) / 2.0;
        g[i] = exp(-(ax * ax) / (2.0 * 1.5 * 1.5));
        s += g[i];
    }
    for (int i = 0; i < WSZ; ++i) wa.w[i] = (float)(g[i] / s);

    const float inv_n = (float)(1.0 / (3.0 * (double)OSZ * (double)OSZ));

    dim3 grid(NCHUNK, 48);
    ssim_vshift<<<grid, NT, 0, stream>>>(raw, dst, out, wa, inv_n);
}